// Round 1
// baseline (199.340 us; speedup 1.0000x reference)
//
#include <hip/hip_runtime.h>
#include <hip/hip_bf16.h>
#include <math.h>

typedef unsigned short u16;
typedef unsigned int   u32;
typedef unsigned long long u64;
typedef __attribute__((ext_vector_type(8))) short bf16x8;
typedef __attribute__((ext_vector_type(4))) short bf16x4;
typedef __attribute__((ext_vector_type(4))) float f32x4;

#define B_   2
#define S_   2048
#define HID_ 1024
#define NH_  16
#define HD_  64
#define MR_  (B_*S_)   // 4096 rows

__device__ __forceinline__ u16 f2bf(float f) {
  union { float f; u32 u; } x; x.f = f;
  u32 r = x.u + 0x7fffu + ((x.u >> 16) & 1u);
  return (u16)(r >> 16);
}
__device__ __forceinline__ float bf2f(u16 h) {
  union { u32 u; float f; } x; x.u = ((u32)h) << 16;
  return x.f;
}
__device__ __forceinline__ void gload16(const void* g, void* l) {
  __builtin_amdgcn_global_load_lds(
      (const __attribute__((address_space(1))) u32*)g,
      (__attribute__((address_space(3))) u32*)l, 16, 0, 0);
}

// ---------------- f32 -> bf16 convert ----------------
__global__ void k_cvt(const float* __restrict__ src, u16* __restrict__ dst, int n4) {
  int i = blockIdx.x * blockDim.x + threadIdx.x;
  if (i < n4) {
    float4 v = ((const float4*)src)[i];
    ushort4 o;
    o.x = f2bf(v.x); o.y = f2bf(v.y); o.z = f2bf(v.z); o.w = f2bf(v.w);
    ((ushort4*)dst)[i] = o;
  }
}

// ---------------- rope table (exact reference gather semantics) ----------------
// sin_u[p][j] = (j<16) ? sin(p*invf[2j])   : cos(p*invf[2j-32])
// cos_u[p][j] = (j<16) ? sin(p*invf[2j+1]) : cos(p*invf[2j-31])
// invf[idx] = 10000^(-idx/32)
__global__ void k_rope_table(float2* __restrict__ tab) {
  int p = blockIdx.x, j = threadIdx.x;  // p<2048, j<32
  double fp = (double)p;
  double c, s;
  if (j < 16) {
    s = sin(fp * pow(10000.0, -(2.0 * j) / 32.0));
    c = sin(fp * pow(10000.0, -(2.0 * j + 1.0) / 32.0));
  } else {
    s = cos(fp * pow(10000.0, -(2.0 * j - 32.0) / 32.0));
    c = cos(fp * pow(10000.0, -(2.0 * j - 31.0) / 32.0));
  }
  tab[p * 32 + j] = make_float2((float)c, (float)s);
}

// ---------------- rope apply: x[4096][1024] -> o[4096][1024], per head ----------------
__global__ void k_rope_apply(const u16* __restrict__ x, const float2* __restrict__ tab,
                             u16* __restrict__ o, float scale) {
  int t = blockIdx.x * blockDim.x + threadIdx.x;   // 4096*512 total
  int row = t >> 9;
  int rem = t & 511;
  int h = rem >> 5, j = rem & 31;
  int s = row & (S_ - 1);
  u32 v = *(const u32*)&x[row * HID_ + h * HD_ + 2 * j];
  float xe = bf2f((u16)(v & 0xffffu));
  float xo = bf2f((u16)(v >> 16));
  float2 cs = tab[s * 32 + j];
  float r0 = (xe * cs.x - xo * cs.y) * scale;
  float r1 = (xe * cs.y + xo * cs.x) * scale;
  o[row * HID_ + h * HD_ + j]      = f2bf(r0);
  o[row * HID_ + h * HD_ + 32 + j] = f2bf(r1);
}

// ---------------- transpose v[4096][1024] -> vt[b][h][d][s] ----------------
__global__ void k_transpose_v(const u16* __restrict__ v, u16* __restrict__ vt) {
  __shared__ u16 tl[32][36];
  int tx = blockIdx.x;   // 0..127 : (b,s) tiles of 32
  int ty = blockIdx.y;   // 0..31  : col tiles of 32
  int t = threadIdx.x;
  int r = t >> 3, c4 = (t & 7) * 4;
  u64 w = *(const u64*)&v[(size_t)(tx * 32 + r) * HID_ + ty * 32 + c4];
  tl[r][c4 + 0] = (u16)(w);
  tl[r][c4 + 1] = (u16)(w >> 16);
  tl[r][c4 + 2] = (u16)(w >> 32);
  tl[r][c4 + 3] = (u16)(w >> 48);
  __syncthreads();
  int dr = t >> 3, s4 = (t & 7) * 4;
  int b = (tx * 32) >> 11;
  int s0 = (tx * 32) & (S_ - 1);
  int h = ty >> 1, d0 = (ty & 1) * 32;
  u64 pk = (u64)tl[s4 + 0][dr] | ((u64)tl[s4 + 1][dr] << 16) |
           ((u64)tl[s4 + 2][dr] << 32) | ((u64)tl[s4 + 3][dr] << 48);
  *(u64*)&vt[(size_t)((b * NH_ + h) * HD_ + d0 + dr) * S_ + s0 + s4] = pk;
}

// ---------------- GEMM: C[M][1024-slice] = A[M][K] @ W^T, 128x128 tile, BK=64 ----------------
template <bool OUTF32>
__global__ __launch_bounds__(256) void k_gemm_bt(
    const u16* __restrict__ A,
    const u16* __restrict__ W0, const u16* __restrict__ W1, const u16* __restrict__ W2,
    u16* __restrict__ O0, u16* __restrict__ O1, u16* __restrict__ O2,
    float* __restrict__ OF, int K) {
  __shared__ __align__(16) u16 Al[128 * 64];
  __shared__ __align__(16) u16 Bl[128 * 64];

  int tid = threadIdx.x;
  int lane = tid & 63, wave = tid >> 6;
  int m0 = blockIdx.y * 128;
  int nt0 = blockIdx.x * 128;
  int wi = nt0 >> 10;
  const u16* W = (wi == 0) ? W0 : (wi == 1 ? W1 : W2);
  int n0 = nt0 & 1023;
  int wm = wave >> 1, wn = wave & 1;
  int lg = lane >> 4, lr = lane & 15;

  f32x4 acc[4][4];
  const f32x4 vz = {0.f, 0.f, 0.f, 0.f};
#pragma unroll
  for (int i = 0; i < 4; ++i)
#pragma unroll
    for (int j = 0; j < 4; ++j) acc[i][j] = vz;

  int chunk = wave * 64 + lane;

  for (int k0 = 0; k0 < K; k0 += 64) {
#pragma unroll
    for (int it = 0; it < 4; ++it) {
      int c = it * 256 + chunk;
      int row = c >> 3;
      int cw = (c & 7) ^ (row & 7);   // pre-swizzled source
      gload16(&A[(size_t)(m0 + row) * K + k0 + cw * 8], &Al[(it * 256 + wave * 64) * 8]);
    }
#pragma unroll
    for (int it = 0; it < 4; ++it) {
      int c = it * 256 + chunk;
      int row = c >> 3;
      int cw = (c & 7) ^ (row & 7);
      gload16(&W[(size_t)(n0 + row) * K + k0 + cw * 8], &Bl[(it * 256 + wave * 64) * 8]);
    }
    __syncthreads();
#pragma unroll
    for (int kk = 0; kk < 2; ++kk) {
      bf16x8 af[4], bfr[4];
#pragma unroll
      for (int mi = 0; mi < 4; ++mi) {
        int row = wm * 64 + mi * 16 + lr;
        int ci = (kk * 4 + lg) ^ (row & 7);
        af[mi] = *(const bf16x8*)&Al[row * 64 + ci * 8];
      }
#pragma unroll
      for (int ni = 0; ni < 4; ++ni) {
        int row = wn * 64 + ni * 16 + lr;
        int ci = (kk * 4 + lg) ^ (row & 7);
        bfr[ni] = *(const bf16x8*)&Bl[row * 64 + ci * 8];
      }
#pragma unroll
      for (int mi = 0; mi < 4; ++mi)
#pragma unroll
        for (int ni = 0; ni < 4; ++ni)
          acc[mi][ni] = __builtin_amdgcn_mfma_f32_16x16x32_bf16(af[mi], bfr[ni], acc[mi][ni], 0, 0, 0);
    }
    __syncthreads();
  }

  // epilogue
  u16* OB = (wi == 0) ? O0 : (wi == 1 ? O1 : O2);
#pragma unroll
  for (int mi = 0; mi < 4; ++mi) {
#pragma unroll
    for (int ni = 0; ni < 4; ++ni) {
#pragma unroll
      for (int r = 0; r < 4; ++r) {
        int grow = m0 + wm * 64 + mi * 16 + lg * 4 + r;
        int gcol = n0 + wn * 64 + ni * 16 + lr;
        float v = acc[mi][ni][r];
        if (OUTF32) OF[(size_t)grow * 1024 + gcol] = v;
        else        OB[(size_t)grow * 1024 + gcol] = f2bf(v);
      }
    }
  }
}

// ---------------- flash attention ----------------
// Q pre-scaled by 1/8. Layouts: Q,K: [4096][1024] bf16; VT: [32][64][2048] bf16.
// Per block: 128 q-rows (4 waves x 32). KV tile = 32 keys.
__global__ __launch_bounds__(256) void k_attn(
    const u16* __restrict__ Q, const u16* __restrict__ Kr, const u16* __restrict__ VT,
    u16* __restrict__ O) {
  __shared__ __align__(16) u16 Kl[32 * 64];
  __shared__ __align__(16) u16 Vl[64 * 40];   // padded stride 40 elems

  int tid = threadIdx.x, lane = tid & 63, wave = tid >> 6;
  int bh = blockIdx.y;
  int b = bh >> 4, h = bh & 15;
  int q0b = blockIdx.x * 128;
  int q0w = q0b + wave * 32;
  int lg = lane >> 4, lr = lane & 15;
  int myq = q0w + 31;

  // Q fragments (B operand of swapped QK^T): qf[q2][kk]
  bf16x8 qf[2][2];
#pragma unroll
  for (int q2 = 0; q2 < 2; ++q2)
#pragma unroll
    for (int kk = 0; kk < 2; ++kk)
      qf[q2][kk] = *(const bf16x8*)&Q[(size_t)(b * S_ + q0w + q2 * 16 + lr) * HID_ + h * HD_ + kk * 32 + lg * 8];

  f32x4 acc[4][2];
  const f32x4 vz = {0.f, 0.f, 0.f, 0.f};
#pragma unroll
  for (int d = 0; d < 4; ++d) { acc[d][0] = vz; acc[d][1] = vz; }
  float mi_[2] = {-1e30f, -1e30f};
  float li_[2] = {0.f, 0.f};

  int nkt = (q0b >> 5) + 4;
  const u16* vtb = &VT[(size_t)bh * HD_ * S_];

  for (int kt = 0; kt < nkt; ++kt) {
    {   // stage K tile 32x64 (swizzled source -> linear LDS)
      int c = wave * 64 + lane;
      int row = c >> 3;
      int cw = (c & 7) ^ (row & 7);
      gload16(&Kr[(size_t)(b * S_ + kt * 32 + row) * HID_ + h * HD_ + cw * 8], &Kl[(wave * 64) * 8]);
    }
    {   // stage VT tile 64x32 into padded LDS (reg-staged, b128 write)
      int dr = tid >> 2, kc = tid & 3;
      bf16x8 vv = *(const bf16x8*)&vtb[(size_t)dr * S_ + kt * 32 + kc * 8];
      *(bf16x8*)&Vl[dr * 40 + kc * 8] = vv;
    }
    __syncthreads();

    if (kt * 32 <= myq) {
      // S^T = K . Q^T   (rows = keys, cols = q)
      f32x4 st[2][2];
      st[0][0] = vz; st[0][1] = vz; st[1][0] = vz; st[1][1] = vz;
#pragma unroll
      for (int kk = 0; kk < 2; ++kk) {
#pragma unroll
        for (int kf = 0; kf < 2; ++kf) {
          int row = kf * 16 + lr;
          int ci = (kk * 4 + lg) ^ (row & 7);
          bf16x8 kfr = *(const bf16x8*)&Kl[row * 64 + ci * 8];
#pragma unroll
          for (int q2 = 0; q2 < 2; ++q2)
            st[kf][q2] = __builtin_amdgcn_mfma_f32_16x16x32_bf16(kfr, qf[q2][kk], st[kf][q2], 0, 0, 0);
        }
      }
      // online softmax (per q-row, lane-local: col = lr)
      bf16x4 pbm[2][2];   // [q2][kf]
#pragma unroll
      for (int q2 = 0; q2 < 2; ++q2) {
        int qg = q0w + q2 * 16 + lr;
        float p[2][4];
        float mt = -1e30f;
#pragma unroll
        for (int kf = 0; kf < 2; ++kf)
#pragma unroll
          for (int r = 0; r < 4; ++r) {
            int kg = kt * 32 + kf * 16 + lg * 4 + r;
            float v = (kg <= qg) ? st[kf][q2][r] : -1e30f;
            p[kf][r] = v;
            mt = fmaxf(mt, v);
          }
        mt = fmaxf(mt, __shfl_xor(mt, 16));
        mt = fmaxf(mt, __shfl_xor(mt, 32));
        float mn = fmaxf(mi_[q2], mt);
        float sc = __expf(mi_[q2] - mn);
        float ts = 0.f;
#pragma unroll
        for (int kf = 0; kf < 2; ++kf)
#pragma unroll
          for (int r = 0; r < 4; ++r) {
            float e = __expf(p[kf][r] - mn);
            p[kf][r] = e;
            ts += e;
          }
        ts += __shfl_xor(ts, 16);
        ts += __shfl_xor(ts, 32);
        li_[q2] = li_[q2] * sc + ts;
        mi_[q2] = mn;
#pragma unroll
        for (int df = 0; df < 4; ++df) acc[df][q2] *= sc;
#pragma unroll
        for (int kf = 0; kf < 2; ++kf) {
          bf16x4 pb;
          pb[0] = (short)f2bf(p[kf][0]);
          pb[1] = (short)f2bf(p[kf][1]);
          pb[2] = (short)f2bf(p[kf][2]);
          pb[3] = (short)f2bf(p[kf][3]);
          pbm[q2][kf] = pb;
        }
      }
      // O^T += V^T . P^T
#pragma unroll
      for (int df = 0; df < 4; ++df) {
#pragma unroll
        for (int kf = 0; kf < 2; ++kf) {
          bf16x4 vfr = *(const bf16x4*)&Vl[(df * 16 + lr) * 40 + kf * 16 + lg * 4];
#pragma unroll
          for (int q2 = 0; q2 < 2; ++q2)
            acc[df][q2] = __builtin_amdgcn_mfma_f32_16x16x16bf16_1k(vfr, pbm[q2][kf], acc[df][q2], 0, 0, 0);
        }
      }
    }
    __syncthreads();
  }

  // epilogue: O[q][h*64+d] = acc / l
#pragma unroll
  for (int q2 = 0; q2 < 2; ++q2) {
    float inv = 1.0f / li_[q2];
    int grow = b * S_ + q0w + q2 * 16 + lr;
#pragma unroll
    for (int df = 0; df < 4; ++df) {
      u64 pk = (u64)f2bf(acc[df][q2][0] * inv) |
               ((u64)f2bf(acc[df][q2][1] * inv) << 16) |
               ((u64)f2bf(acc[df][q2][2] * inv) << 32) |
               ((u64)f2bf(acc[df][q2][3] * inv) << 48);
      *(u64*)&O[(size_t)grow * HID_ + h * HD_ + df * 16 + lg * 4] = pk;
    }
  }
}

// ---------------- launch ----------------
extern "C" void kernel_launch(void* const* d_in, const int* in_sizes, int n_in,
                              void* d_out, int out_size, void* d_ws, size_t ws_size,
                              hipStream_t stream) {
  const float* hs = (const float*)d_in[0];
  // d_in[1] attention_mask: deterministic causal, implemented in-kernel
  const float* wq = (const float*)d_in[2];
  const float* wk = (const float*)d_in[3];
  const float* wv = (const float*)d_in[4];
  const float* wo = (const float*)d_in[5];
  float* out = (float*)d_out;

  char* ws = (char*)d_ws;
  const size_t P = (size_t)MR_ * HID_ * 2;   // 8 MiB plane
  u16* Xb    = (u16*)(ws);                   // reused as q_r after QKV GEMM
  u16* Wqb   = (u16*)(ws + P);
  u16* Wkb   = (u16*)(ws + P + (size_t)HID_ * HID_ * 2);
  u16* Wvb   = (u16*)(ws + P + (size_t)HID_ * HID_ * 4);
  u16* Wob   = (u16*)(ws + P + (size_t)HID_ * HID_ * 6);
  u16* q_tmp = (u16*)(ws + 2 * P);           // reused as attn_out after rope
  u16* k_tmp = (u16*)(ws + 3 * P);
  u16* v_tmp = (u16*)(ws + 4 * P);
  u16* k_r   = (u16*)(ws + 5 * P);
  u16* vt    = (u16*)(ws + 6 * P);
  float2* tab = (float2*)(ws + 7 * P);
  u16* q_r = Xb;
  u16* attn_o = q_tmp;

  // converts
  k_cvt<<<(MR_ * HID_ / 4 + 255) / 256, 256, 0, stream>>>(hs, Xb, MR_ * HID_ / 4);
  k_cvt<<<(HID_ * HID_ / 4 + 255) / 256, 256, 0, stream>>>(wq, Wqb, HID_ * HID_ / 4);
  k_cvt<<<(HID_ * HID_ / 4 + 255) / 256, 256, 0, stream>>>(wk, Wkb, HID_ * HID_ / 4);
  k_cvt<<<(HID_ * HID_ / 4 + 255) / 256, 256, 0, stream>>>(wv, Wvb, HID_ * HID_ / 4);
  k_cvt<<<(HID_ * HID_ / 4 + 255) / 256, 256, 0, stream>>>(wo, Wob, HID_ * HID_ / 4);
  k_rope_table<<<S_, 32, 0, stream>>>(tab);

  // QKV projections (fused, N = 3072)
  k_gemm_bt<false><<<dim3(24, 32), 256, 0, stream>>>(
      Xb, Wqb, Wkb, Wvb, q_tmp, k_tmp, v_tmp, nullptr, HID_);

  // rope (q scaled by 1/sqrt(HD))
  k_rope_apply<<<MR_ * 512 / 256, 256, 0, stream>>>(q_tmp, tab, q_r, 0.125f);
  k_rope_apply<<<MR_ * 512 / 256, 256, 0, stream>>>(k_tmp, tab, k_r, 1.0f);

  // V transpose
  k_transpose_v<<<dim3(MR_ / 32, HID_ / 32), 256, 0, stream>>>(v_tmp, vt);

  // attention
  k_attn<<<dim3(S_ / 128, B_ * NH_), 256, 0, stream>>>(q_r, k_r, vt, attn_o);

  // output projection -> f32
  k_gemm_bt<true><<<dim3(8, 32), 256, 0, stream>>>(
      attn_o, Wob, Wob, Wob, nullptr, nullptr, nullptr, out, HID_);
}

// Round 2
// 157.572 us; speedup vs baseline: 1.2651x; 1.2651x over previous
//
#include <hip/hip_runtime.h>
#include <hip/hip_bf16.h>
#include <math.h>

typedef unsigned short u16;
typedef unsigned int   u32;
typedef unsigned long long u64;
typedef __attribute__((ext_vector_type(8))) short bf16x8;
typedef __attribute__((ext_vector_type(4))) short bf16x4;
typedef __attribute__((ext_vector_type(4))) float f32x4;

#define B_   2
#define S_   2048
#define HID_ 1024
#define NH_  16
#define HD_  64
#define MR_  (B_*S_)   // 4096 rows

__device__ __forceinline__ u16 f2bf(float f) {
  union { float f; u32 u; } x; x.f = f;
  u32 r = x.u + 0x7fffu + ((x.u >> 16) & 1u);
  return (u16)(r >> 16);
}
__device__ __forceinline__ float bf2f(u16 h) {
  union { u32 u; float f; } x; x.u = ((u32)h) << 16;
  return x.f;
}
__device__ __forceinline__ void gload16(const void* g, void* l) {
  __builtin_amdgcn_global_load_lds(
      (const __attribute__((address_space(1))) u32*)g,
      (__attribute__((address_space(3))) u32*)l, 16, 0, 0);
}

// ---------------- fused f32 -> bf16 convert (hs + 4 weights) ----------------
__global__ void k_cvt_all(const float* __restrict__ hs, const float* __restrict__ wq,
                          const float* __restrict__ wk, const float* __restrict__ wv,
                          const float* __restrict__ wo, ushort4* __restrict__ dst) {
  int i = blockIdx.x * blockDim.x + threadIdx.x;   // < 2097152
  const float4* src;
  int idx;
  if (i < 1048576) {
    src = (const float4*)hs; idx = i;
  } else {
    int j = i - 1048576;
    int w = j >> 18; idx = j & 262143;
    src = (const float4*)(w == 0 ? wq : w == 1 ? wk : w == 2 ? wv : wo);
  }
  float4 v = src[idx];
  ushort4 o;
  o.x = f2bf(v.x); o.y = f2bf(v.y); o.z = f2bf(v.z); o.w = f2bf(v.w);
  dst[i] = o;
}

// ---------------- rope table (exact reference gather semantics) ----------------
__global__ void k_rope_table(float2* __restrict__ tab) {
  int t = blockIdx.x * blockDim.x + threadIdx.x;   // < 65536
  int p = t >> 5, j = t & 31;
  double fp = (double)p;
  double c, s;
  if (j < 16) {
    s = sin(fp * pow(10000.0, -(2.0 * j) / 32.0));
    c = sin(fp * pow(10000.0, -(2.0 * j + 1.0) / 32.0));
  } else {
    s = cos(fp * pow(10000.0, -(2.0 * j - 32.0) / 32.0));
    c = cos(fp * pow(10000.0, -(2.0 * j - 31.0) / 32.0));
  }
  tab[p * 32 + j] = make_float2((float)c, (float)s);
}

// ---------------- fused rope apply for q and k ----------------
__global__ void k_rope2(const u16* __restrict__ qi, const u16* __restrict__ ki,
                        const float2* __restrict__ tab,
                        u16* __restrict__ qo, u16* __restrict__ ko) {
  int t = blockIdx.x * blockDim.x + threadIdx.x;   // < 2*2^21
  int selk = t >> 21;
  int u = t & ((1 << 21) - 1);
  int row = u >> 9;
  int rem = u & 511;
  int h = rem >> 5, j = rem & 31;
  int s = row & (S_ - 1);
  const u16* x = selk ? ki : qi;
  u16* o = selk ? ko : qo;
  float scale = selk ? 1.0f : 0.125f;
  u32 v = *(const u32*)&x[row * HID_ + h * HD_ + 2 * j];
  float xe = bf2f((u16)(v & 0xffffu));
  float xo = bf2f((u16)(v >> 16));
  float2 cs = tab[s * 32 + j];
  float r0 = (xe * cs.x - xo * cs.y) * scale;
  float r1 = (xe * cs.y + xo * cs.x) * scale;
  o[row * HID_ + h * HD_ + j]      = f2bf(r0);
  o[row * HID_ + h * HD_ + 32 + j] = f2bf(r1);
}

// ---------------- transpose v[4096][1024] -> vt[b][h][d][s] ----------------
__global__ void k_transpose_v(const u16* __restrict__ v, u16* __restrict__ vt) {
  __shared__ u16 tl[32][36];
  int tx = blockIdx.x;
  int ty = blockIdx.y;
  int t = threadIdx.x;
  int r = t >> 3, c4 = (t & 7) * 4;
  u64 w = *(const u64*)&v[(size_t)(tx * 32 + r) * HID_ + ty * 32 + c4];
  tl[r][c4 + 0] = (u16)(w);
  tl[r][c4 + 1] = (u16)(w >> 16);
  tl[r][c4 + 2] = (u16)(w >> 32);
  tl[r][c4 + 3] = (u16)(w >> 48);
  __syncthreads();
  int dr = t >> 3, s4 = (t & 7) * 4;
  int b = (tx * 32) >> 11;
  int s0 = (tx * 32) & (S_ - 1);
  int h = ty >> 1, d0 = (ty & 1) * 32;
  u64 pk = (u64)tl[s4 + 0][dr] | ((u64)tl[s4 + 1][dr] << 16) |
           ((u64)tl[s4 + 2][dr] << 32) | ((u64)tl[s4 + 3][dr] << 48);
  *(u64*)&vt[(size_t)((b * NH_ + h) * HD_ + d0 + dr) * S_ + s0 + s4] = pk;
}

// ---------------- GEMM: C[M][1024-slice] = A[M][K] @ W^T, 128x128 tile, BK=64 ----------------
template <bool OUTF32>
__global__ __launch_bounds__(256) void k_gemm_bt(
    const u16* __restrict__ A,
    const u16* __restrict__ W0, const u16* __restrict__ W1, const u16* __restrict__ W2,
    u16* __restrict__ O0, u16* __restrict__ O1, u16* __restrict__ O2,
    float* __restrict__ OF, int K) {
  __shared__ __align__(16) u16 Al[128 * 64];
  __shared__ __align__(16) u16 Bl[128 * 64];

  int tid = threadIdx.x;
  int lane = tid & 63, wave = tid >> 6;
  int m0 = blockIdx.y * 128;
  int nt0 = blockIdx.x * 128;
  int wi = nt0 >> 10;
  const u16* W = (wi == 0) ? W0 : (wi == 1 ? W1 : W2);
  int n0 = nt0 & 1023;
  int wm = wave >> 1, wn = wave & 1;
  int lg = lane >> 4, lr = lane & 15;

  f32x4 acc[4][4];
  const f32x4 vz = {0.f, 0.f, 0.f, 0.f};
#pragma unroll
  for (int i = 0; i < 4; ++i)
#pragma unroll
    for (int j = 0; j < 4; ++j) acc[i][j] = vz;

  int chunk = wave * 64 + lane;

  for (int k0 = 0; k0 < K; k0 += 64) {
#pragma unroll
    for (int it = 0; it < 4; ++it) {
      int c = it * 256 + chunk;
      int row = c >> 3;
      int cw = (c & 7) ^ (row & 7);
      gload16(&A[(size_t)(m0 + row) * K + k0 + cw * 8], &Al[(it * 256 + wave * 64) * 8]);
    }
#pragma unroll
    for (int it = 0; it < 4; ++it) {
      int c = it * 256 + chunk;
      int row = c >> 3;
      int cw = (c & 7) ^ (row & 7);
      gload16(&W[(size_t)(n0 + row) * K + k0 + cw * 8], &Bl[(it * 256 + wave * 64) * 8]);
    }
    __syncthreads();
#pragma unroll
    for (int kk = 0; kk < 2; ++kk) {
      bf16x8 af[4], bfr[4];
#pragma unroll
      for (int mi = 0; mi < 4; ++mi) {
        int row = wm * 64 + mi * 16 + lr;
        int ci = (kk * 4 + lg) ^ (row & 7);
        af[mi] = *(const bf16x8*)&Al[row * 64 + ci * 8];
      }
#pragma unroll
      for (int ni = 0; ni < 4; ++ni) {
        int row = wn * 64 + ni * 16 + lr;
        int ci = (kk * 4 + lg) ^ (row & 7);
        bfr[ni] = *(const bf16x8*)&Bl[row * 64 + ci * 8];
      }
#pragma unroll
      for (int mi = 0; mi < 4; ++mi)
#pragma unroll
        for (int ni = 0; ni < 4; ++ni)
          acc[mi][ni] = __builtin_amdgcn_mfma_f32_16x16x32_bf16(af[mi], bfr[ni], acc[mi][ni], 0, 0, 0);
    }
    __syncthreads();
  }

  u16* OB = (wi == 0) ? O0 : (wi == 1 ? O1 : O2);
#pragma unroll
  for (int mi = 0; mi < 4; ++mi) {
#pragma unroll
    for (int ni = 0; ni < 4; ++ni) {
#pragma unroll
      for (int r = 0; r < 4; ++r) {
        int grow = m0 + wm * 64 + mi * 16 + lg * 4 + r;
        int gcol = n0 + wn * 64 + ni * 16 + lr;
        float v = acc[mi][ni][r];
        if (OUTF32) OF[(size_t)grow * 1024 + gcol] = v;
        else        OB[(size_t)grow * 1024 + gcol] = f2bf(v);
      }
    }
  }
}

// ---------------- flash attention, paired q-tiles, KVBLK=64, double-buffered ----------------
// Q pre-scaled by 1/8. Q,K: [4096][1024] bf16; VT: [32][64][2048] bf16.
// Grid: (8 pairs, 32 bh). Block: 4 waves. Wave w: 32 q-rows of tile p + 32 of tile 15-p.
__global__ __launch_bounds__(256) void k_attn(
    const u16* __restrict__ Q, const u16* __restrict__ Kr, const u16* __restrict__ VT,
    u16* __restrict__ O) {
  __shared__ __align__(16) u16 Kl[2][64 * 64];
  __shared__ __align__(16) u16 Vl[2][64 * 64];

  int tid = threadIdx.x, lane = tid & 63, wave = tid >> 6;
  int p = blockIdx.x, bh = blockIdx.y;
  int b = bh >> 4, h = bh & 15;
  int lg = lane >> 4, lr = lane & 15;
  int bS = b * S_;

  int q0h[2];
  q0h[0] = p * 128 + wave * 32;
  q0h[1] = (15 - p) * 128 + wave * 32;
  int ktmax[2];
  ktmax[0] = (q0h[0] + 31) >> 6;
  ktmax[1] = (q0h[1] + 31) >> 6;
  int nkt = 32 - 2 * p;

  const u16* vtb = &VT[(size_t)bh * HD_ * S_];
  int l8 = lane >> 3, l7 = lane & 7;
  int sl = l7 ^ l8;   // pre-swizzled global slot

  auto STAGE = [&](int kt_, int bs_) {
#pragma unroll
    for (int it = 0; it < 2; ++it) {
      int rb = wave * 16 + it * 8;           // tile-row base (wave-uniform)
      int r = rb + l8;                        // per-lane row
      gload16(&Kr[(size_t)(bS + kt_ * 64 + r) * HID_ + h * HD_ + sl * 8],
              &Kl[bs_][rb * 64]);
      gload16(&vtb[(size_t)r * S_ + kt_ * 64 + sl * 8],
              &Vl[bs_][rb * 64]);
    }
  };

  // prologue: stage tile 0, then load Q fragments (latency overlaps)
  STAGE(0, 0);

  bf16x8 qf[2][2][2];   // [half][q2][kk]
#pragma unroll
  for (int half = 0; half < 2; ++half)
#pragma unroll
    for (int q2 = 0; q2 < 2; ++q2)
#pragma unroll
      for (int kk = 0; kk < 2; ++kk)
        qf[half][q2][kk] = *(const bf16x8*)
            &Q[(size_t)(bS + q0h[half] + q2 * 16 + lr) * HID_ + h * HD_ + kk * 32 + lg * 8];

  f32x4 acc[2][4][2];
  const f32x4 vz = {0.f, 0.f, 0.f, 0.f};
#pragma unroll
  for (int half = 0; half < 2; ++half)
#pragma unroll
    for (int df = 0; df < 4; ++df)
#pragma unroll
      for (int q2 = 0; q2 < 2; ++q2) acc[half][df][q2] = vz;
  float m_[2][2] = {{-1e30f, -1e30f}, {-1e30f, -1e30f}};
  float l_[2][2] = {{0.f, 0.f}, {0.f, 0.f}};

  for (int kt = 0; kt < nkt; ++kt) {
    int cur = kt & 1;
    if (kt + 1 < nkt) {
      STAGE(kt + 1, cur ^ 1);
      asm volatile("s_waitcnt vmcnt(4)" ::: "memory");
    } else {
      asm volatile("s_waitcnt vmcnt(0)" ::: "memory");
    }
    __builtin_amdgcn_s_barrier();
    __builtin_amdgcn_sched_barrier(0);

    // K fragments (shared by both halves)
    bf16x8 kfr[4][2];
#pragma unroll
    for (int kf = 0; kf < 4; ++kf) {
      int row = kf * 16 + lr;
#pragma unroll
      for (int kk = 0; kk < 2; ++kk) {
        int ci = (kk * 4 + lg) ^ (row & 7);
        kfr[kf][kk] = *(const bf16x8*)&Kl[cur][row * 64 + ci * 8];
      }
    }

#pragma unroll
    for (int half = 0; half < 2; ++half) {
      if (kt <= ktmax[half]) {
        f32x4 st[4][2];
#pragma unroll
        for (int kf = 0; kf < 4; ++kf) { st[kf][0] = vz; st[kf][1] = vz; }
#pragma unroll
        for (int kk = 0; kk < 2; ++kk)
#pragma unroll
          for (int kf = 0; kf < 4; ++kf)
#pragma unroll
            for (int q2 = 0; q2 < 2; ++q2)
              st[kf][q2] = __builtin_amdgcn_mfma_f32_16x16x32_bf16(
                  kfr[kf][kk], qf[half][q2][kk], st[kf][q2], 0, 0, 0);

        bool needMask = (kt == ktmax[half]);
        bf16x4 pb[2][4];
#pragma unroll
        for (int q2 = 0; q2 < 2; ++q2) {
          int qg = q0h[half] + q2 * 16 + lr;
          if (needMask) {
#pragma unroll
            for (int kf = 0; kf < 4; ++kf)
#pragma unroll
              for (int r = 0; r < 4; ++r) {
                int kg = kt * 64 + kf * 16 + lg * 4 + r;
                if (kg > qg) st[kf][q2][r] = -1e30f;
              }
          }
          float mx = m_[half][q2];
#pragma unroll
          for (int kf = 0; kf < 4; ++kf)
#pragma unroll
            for (int r = 0; r < 4; ++r) mx = fmaxf(mx, st[kf][q2][r]);
          mx = fmaxf(mx, __shfl_xor(mx, 16));
          mx = fmaxf(mx, __shfl_xor(mx, 32));
          float sc = __expf(m_[half][q2] - mx);
          float ts = 0.f;
#pragma unroll
          for (int kf = 0; kf < 4; ++kf)
#pragma unroll
            for (int r = 0; r < 4; ++r) {
              float e = __expf(st[kf][q2][r] - mx);
              st[kf][q2][r] = e;
              ts += e;
            }
          ts += __shfl_xor(ts, 16);
          ts += __shfl_xor(ts, 32);
          l_[half][q2] = l_[half][q2] * sc + ts;
          m_[half][q2] = mx;
#pragma unroll
          for (int df = 0; df < 4; ++df) acc[half][df][q2] *= sc;
#pragma unroll
          for (int kf = 0; kf < 4; ++kf) {
            bf16x4 pk;
            pk[0] = (short)f2bf(st[kf][q2][0]);
            pk[1] = (short)f2bf(st[kf][q2][1]);
            pk[2] = (short)f2bf(st[kf][q2][2]);
            pk[3] = (short)f2bf(st[kf][q2][3]);
            pb[q2][kf] = pk;
          }
        }

        // PV for this half: O^T += V^T . P^T
#pragma unroll
        for (int df = 0; df < 4; ++df) {
          int row = df * 16 + lr;
#pragma unroll
          for (int kf = 0; kf < 4; ++kf) {
            int slot = (kf * 2 + (lg >> 1)) ^ (row & 7);
            bf16x4 vfr = *(const bf16x4*)&Vl[cur][row * 64 + slot * 8 + (lg & 1) * 4];
#pragma unroll
            for (int q2 = 0; q2 < 2; ++q2)
              acc[half][df][q2] = __builtin_amdgcn_mfma_f32_16x16x16bf16_1k(
                  vfr, pb[q2][kf], acc[half][df][q2], 0, 0, 0);
          }
        }
      }
    }
    __builtin_amdgcn_sched_barrier(0);
    __builtin_amdgcn_s_barrier();
  }

  // epilogue
#pragma unroll
  for (int half = 0; half < 2; ++half) {
#pragma unroll
    for (int q2 = 0; q2 < 2; ++q2) {
      float inv = 1.0f / l_[half][q2];
      int grow = bS + q0h[half] + q2 * 16 + lr;
#pragma unroll
      for (int df = 0; df < 4; ++df) {
        u64 pk = (u64)f2bf(acc[half][df][q2][0] * inv) |
                 ((u64)f2bf(acc[half][df][q2][1] * inv) << 16) |
                 ((u64)f2bf(acc[half][df][q2][2] * inv) << 32) |
                 ((u64)f2bf(acc[half][df][q2][3] * inv) << 48);
        *(u64*)&O[(size_t)grow * HID_ + h * HD_ + df * 16 + lg * 4] = pk;
      }
    }
  }
}

// ---------------- launch ----------------
extern "C" void kernel_launch(void* const* d_in, const int* in_sizes, int n_in,
                              void* d_out, int out_size, void* d_ws, size_t ws_size,
                              hipStream_t stream) {
  const float* hs = (const float*)d_in[0];
  const float* wq = (const float*)d_in[2];
  const float* wk = (const float*)d_in[3];
  const float* wv = (const float*)d_in[4];
  const float* wo = (const float*)d_in[5];
  float* out = (float*)d_out;

  char* ws = (char*)d_ws;
  const size_t P = (size_t)MR_ * HID_ * 2;   // 8 MiB plane
  u16* Xb    = (u16*)(ws);
  u16* Wqb   = (u16*)(ws + P);
  u16* Wkb   = (u16*)(ws + P + (size_t)HID_ * HID_ * 2);
  u16* Wvb   = (u16*)(ws + P + (size_t)HID_ * HID_ * 4);
  u16* Wob   = (u16*)(ws + P + (size_t)HID_ * HID_ * 6);
  u16* q_tmp = (u16*)(ws + 2 * P);
  u16* k_tmp = (u16*)(ws + 3 * P);
  u16* v_tmp = (u16*)(ws + 4 * P);
  u16* k_r   = (u16*)(ws + 5 * P);
  u16* vt    = (u16*)(ws + 6 * P);
  float2* tab = (float2*)(ws + 7 * P);
  u16* q_r = Xb;
  u16* attn_o = q_tmp;

  // fused converts (hs + 4 weights, contiguous dst starting at ws)
  k_cvt_all<<<8192, 256, 0, stream>>>(hs, wq, wk, wv, wo, (ushort4*)ws);
  k_rope_table<<<256, 256, 0, stream>>>(tab);

  // QKV projections (fused, N = 3072)
  k_gemm_bt<false><<<dim3(24, 32), 256, 0, stream>>>(
      Xb, Wqb, Wkb, Wvb, q_tmp, k_tmp, v_tmp, nullptr, HID_);

  // fused rope for q (scaled 1/8) and k
  k_rope2<<<16384, 256, 0, stream>>>(q_tmp, k_tmp, tab, q_r, k_r);

  // V transpose
  k_transpose_v<<<dim3(MR_ / 32, HID_ / 32), 256, 0, stream>>>(v_tmp, vt);

  // attention (paired causal tiles)
  k_attn<<<dim3(8, 32), 256, 0, stream>>>(q_r, k_r, vt, attn_o);

  // output projection -> f32
  k_gemm_bt<true><<<dim3(8, 32), 256, 0, stream>>>(
      attn_o, Wob, Wob, Wob, nullptr, nullptr, nullptr, out, HID_);
}

// Round 3
// 147.742 us; speedup vs baseline: 1.3492x; 1.0665x over previous
//
#include <hip/hip_runtime.h>
#include <hip/hip_bf16.h>
#include <math.h>

typedef unsigned short u16;
typedef unsigned int   u32;
typedef unsigned long long u64;
typedef __attribute__((ext_vector_type(8))) short bf16x8;
typedef __attribute__((ext_vector_type(4))) short bf16x4;
typedef __attribute__((ext_vector_type(4))) float f32x4;

#define B_   2
#define S_   2048
#define HID_ 1024
#define NH_  16
#define HD_  64
#define MR_  (B_*S_)   // 4096 rows

// 0.125 * log2(e) : folds both the 1/sqrt(64) score scale and the exp->exp2
// conversion into Q at the RoPE epilogue.
#define QSCALE 0.1803368801111137f

__device__ __forceinline__ u16 f2bf(float f) {
  union { float f; u32 u; } x; x.f = f;
  u32 r = x.u + 0x7fffu + ((x.u >> 16) & 1u);
  return (u16)(r >> 16);
}
__device__ __forceinline__ void gload16(const void* g, void* l) {
  __builtin_amdgcn_global_load_lds(
      (const __attribute__((address_space(1))) u32*)g,
      (__attribute__((address_space(3))) u32*)l, 16, 0, 0);
}

// ---------------- fused f32 -> bf16 convert (hs + 4 weights) ----------------
__global__ void k_cvt_all(const float* __restrict__ hs, const float* __restrict__ wq,
                          const float* __restrict__ wk, const float* __restrict__ wv,
                          const float* __restrict__ wo, ushort4* __restrict__ dst) {
  int i = blockIdx.x * blockDim.x + threadIdx.x;   // < 2097152
  const float4* src;
  int idx;
  if (i < 1048576) {
    src = (const float4*)hs; idx = i;
  } else {
    int j = i - 1048576;
    int w = j >> 18; idx = j & 262143;
    src = (const float4*)(w == 0 ? wq : w == 1 ? wk : w == 2 ? wv : wo);
  }
  float4 v = src[idx];
  ushort4 o;
  o.x = f2bf(v.x); o.y = f2bf(v.y); o.z = f2bf(v.z); o.w = f2bf(v.w);
  dst[i] = o;
}

// ---------------- rope table (exact reference gather semantics) ----------------
__global__ void k_rope_table(float2* __restrict__ tab) {
  int t = blockIdx.x * blockDim.x + threadIdx.x;   // < 65536
  int p = t >> 5, j = t & 31;
  double fp = (double)p;
  double c, s;
  if (j < 16) {
    s = sin(fp * pow(10000.0, -(2.0 * j) / 32.0));
    c = sin(fp * pow(10000.0, -(2.0 * j + 1.0) / 32.0));
  } else {
    s = cos(fp * pow(10000.0, -(2.0 * j - 32.0) / 32.0));
    c = cos(fp * pow(10000.0, -(2.0 * j - 31.0) / 32.0));
  }
  tab[p * 32 + j] = make_float2((float)c, (float)s);
}

// ---------------- GEMM: 128x128 tile, BK=64, fused epilogues ----------------
// MODE 0: QKV — wi 0/1 apply RoPE (Q scaled by QSCALE) in-epilogue; wi 2 writes
//         V transposed to vt[bh][d][s].
// MODE 1: f32 output (O-projection).
template <int MODE>
__global__ __launch_bounds__(256) void k_gemm_bt(
    const u16* __restrict__ A,
    const u16* __restrict__ W0, const u16* __restrict__ W1, const u16* __restrict__ W2,
    u16* __restrict__ O0, u16* __restrict__ O1, u16* __restrict__ O2,
    float* __restrict__ OF, const float2* __restrict__ tab, int K) {
  __shared__ __align__(16) u16 Al[128 * 64];
  __shared__ __align__(16) u16 Bl[128 * 64];

  int tid = threadIdx.x;
  int lane = tid & 63, wave = tid >> 6;
  int m0 = blockIdx.y * 128;
  int nt0 = blockIdx.x * 128;
  int wi = nt0 >> 10;
  const u16* W = (wi == 0) ? W0 : (wi == 1 ? W1 : W2);
  int n0 = nt0 & 1023;
  int wm = wave >> 1, wn = wave & 1;
  int lg = lane >> 4, lr = lane & 15;

  f32x4 acc[4][4];
  const f32x4 vz = {0.f, 0.f, 0.f, 0.f};
#pragma unroll
  for (int i = 0; i < 4; ++i)
#pragma unroll
    for (int j = 0; j < 4; ++j) acc[i][j] = vz;

  int chunk = wave * 64 + lane;

  for (int k0 = 0; k0 < K; k0 += 64) {
#pragma unroll
    for (int it = 0; it < 4; ++it) {
      int c = it * 256 + chunk;
      int row = c >> 3;
      int cw = (c & 7) ^ (row & 7);
      gload16(&A[(size_t)(m0 + row) * K + k0 + cw * 8], &Al[(it * 256 + wave * 64) * 8]);
    }
#pragma unroll
    for (int it = 0; it < 4; ++it) {
      int c = it * 256 + chunk;
      int row = c >> 3;
      int cw = (c & 7) ^ (row & 7);
      gload16(&W[(size_t)(n0 + row) * K + k0 + cw * 8], &Bl[(it * 256 + wave * 64) * 8]);
    }
    __syncthreads();
#pragma unroll
    for (int kk = 0; kk < 2; ++kk) {
      bf16x8 af[4], bfr[4];
#pragma unroll
      for (int mi = 0; mi < 4; ++mi) {
        int row = wm * 64 + mi * 16 + lr;
        int ci = (kk * 4 + lg) ^ (row & 7);
        af[mi] = *(const bf16x8*)&Al[row * 64 + ci * 8];
      }
#pragma unroll
      for (int ni = 0; ni < 4; ++ni) {
        int row = wn * 64 + ni * 16 + lr;
        int ci = (kk * 4 + lg) ^ (row & 7);
        bfr[ni] = *(const bf16x8*)&Bl[row * 64 + ci * 8];
      }
#pragma unroll
      for (int mi = 0; mi < 4; ++mi)
#pragma unroll
        for (int ni = 0; ni < 4; ++ni)
          acc[mi][ni] = __builtin_amdgcn_mfma_f32_16x16x32_bf16(af[mi], bfr[ni], acc[mi][ni], 0, 0, 0);
    }
    __syncthreads();
  }

  if (MODE == 1) {
#pragma unroll
    for (int mi = 0; mi < 4; ++mi)
#pragma unroll
      for (int ni = 0; ni < 4; ++ni)
#pragma unroll
        for (int r = 0; r < 4; ++r) {
          int grow = m0 + wm * 64 + mi * 16 + lg * 4 + r;
          int gcol = n0 + wn * 64 + ni * 16 + lr;
          OF[(size_t)grow * 1024 + gcol] = acc[mi][ni][r];
        }
    return;
  }

  // MODE 0 epilogues
  if (wi == 2) {
    // V: write transposed vt[((b*16+h)*64 + d)*2048 + s], 4 rows packed per u64
#pragma unroll
    for (int mi = 0; mi < 4; ++mi) {
      int grow0 = m0 + wm * 64 + mi * 16 + lg * 4;
      int bb = grow0 >> 11;
      int s = grow0 & 2047;
#pragma unroll
      for (int ni = 0; ni < 4; ++ni) {
        int gcol = n0 + wn * 64 + ni * 16 + lr;
        int h = gcol >> 6, dd = gcol & 63;
        u64 pk = (u64)f2bf(acc[mi][ni][0]) |
                 ((u64)f2bf(acc[mi][ni][1]) << 16) |
                 ((u64)f2bf(acc[mi][ni][2]) << 32) |
                 ((u64)f2bf(acc[mi][ni][3]) << 48);
        *(u64*)&O2[((size_t)(bb * NH_ + h) * HD_ + dd) * S_ + s] = pk;
      }
    }
  } else {
    // Q / K: RoPE in-epilogue. Pair (2j, 2j+1) lives in lanes (lr even, lr odd).
    u16* OB = wi ? O1 : O0;
    float sc = wi ? 1.0f : QSCALE;
#pragma unroll
    for (int mi = 0; mi < 4; ++mi) {
#pragma unroll
      for (int ni = 0; ni < 4; ++ni) {
        int gcol = n0 + wn * 64 + ni * 16 + lr;
        int h = gcol >> 6;
        int j = (gcol & 63) >> 1;
        bool even = !(gcol & 1);
        int ocol = h * 64 + (even ? j : 32 + j);
#pragma unroll
        for (int r = 0; r < 4; ++r) {
          float val = acc[mi][ni][r];
          float pv = __shfl_xor(val, 1);
          int grow = m0 + wm * 64 + mi * 16 + lg * 4 + r;
          int s = grow & 2047;
          float2 cs = tab[s * 32 + j];
          float xe = even ? val : pv;
          float xo = even ? pv : val;
          float res = even ? (xe * cs.x - xo * cs.y) : (xe * cs.y + xo * cs.x);
          OB[(size_t)grow * 1024 + ocol] = f2bf(res * sc);
        }
      }
    }
  }
}

// ---------------- flash attention v3 ----------------
// 64-row q-tiles paired (i, 31-i); 4 waves x 16 rows/half; KVBLK=64, dbuf,
// counted vmcnt; log2-domain softmax (Q pre-scaled by QSCALE); defer-max.
// Grid: 512 blocks 1D, XCD-swizzled so each XCD owns 4 consecutive bh.
__global__ __launch_bounds__(256) void k_attn(
    const u16* __restrict__ Q, const u16* __restrict__ Kr, const u16* __restrict__ VT,
    u16* __restrict__ O) {
  __shared__ __align__(16) u16 Kl[2][64 * 64];
  __shared__ __align__(16) u16 Vl[2][64 * 64];

  int tid = threadIdx.x, lane = tid & 63, wave = tid >> 6;
  int d0 = blockIdx.x;                 // 0..511
  int jj = d0 >> 3;
  int qt = jj & 15;                    // q-tile pair index
  int bh = (d0 & 7) * 4 + (jj >> 4);   // XCD (d0&7) owns bh group of 4
  int b = bh >> 4, h = bh & 15;
  int lg = lane >> 4, lr = lane & 15;
  int bS = b * S_;

  int q0h[2] = { qt * 64 + wave * 16, (31 - qt) * 64 + wave * 16 };
  int ktmax0 = qt, ktmax1 = 31 - qt;
  int nkt = 32 - qt;

  const u16* vtb = &VT[(size_t)bh * HD_ * S_];
  int l8 = lane >> 3, l7 = lane & 7;
  int sl = l7 ^ l8;   // pre-swizzled global slot

  auto STAGE = [&](int kt_, int bs_) {
#pragma unroll
    for (int it = 0; it < 2; ++it) {
      int rb = wave * 16 + it * 8;     // wave-uniform LDS row base
      int r = rb + l8;
      gload16(&Kr[(size_t)(bS + kt_ * 64 + r) * HID_ + h * HD_ + sl * 8],
              &Kl[bs_][rb * 64]);
      gload16(&vtb[(size_t)r * S_ + kt_ * 64 + sl * 8],
              &Vl[bs_][rb * 64]);
    }
  };

  STAGE(0, 0);

  bf16x8 qf[2][2];   // [half][kk]
#pragma unroll
  for (int half = 0; half < 2; ++half)
#pragma unroll
    for (int kk = 0; kk < 2; ++kk)
      qf[half][kk] = *(const bf16x8*)
          &Q[(size_t)(bS + q0h[half] + lr) * HID_ + h * HD_ + kk * 32 + lg * 8];

  f32x4 acc[2][4];
  const f32x4 vz = {0.f, 0.f, 0.f, 0.f};
#pragma unroll
  for (int half = 0; half < 2; ++half)
#pragma unroll
    for (int df = 0; df < 4; ++df) acc[half][df] = vz;
  float m_[2] = {-1e30f, -1e30f};
  float l_[2] = {0.f, 0.f};

  for (int kt = 0; kt < nkt; ++kt) {
    int cur = kt & 1;
    if (kt + 1 < nkt) {
      STAGE(kt + 1, cur ^ 1);
      asm volatile("s_waitcnt vmcnt(4)" ::: "memory");
    } else {
      asm volatile("s_waitcnt vmcnt(0)" ::: "memory");
    }
    __builtin_amdgcn_s_barrier();
    __builtin_amdgcn_sched_barrier(0);

    // K fragments (shared by both halves)
    bf16x8 kfr[4][2];
#pragma unroll
    for (int kf = 0; kf < 4; ++kf) {
      int row = kf * 16 + lr;
#pragma unroll
      for (int kk = 0; kk < 2; ++kk) {
        int ci = (kk * 4 + lg) ^ (row & 7);
        kfr[kf][kk] = *(const bf16x8*)&Kl[cur][row * 64 + ci * 8];
      }
    }

#pragma unroll
    for (int half = 0; half < 2; ++half) {
      int ktm = half ? ktmax1 : ktmax0;
      if (kt <= ktm) {
        f32x4 st[4];
#pragma unroll
        for (int kf = 0; kf < 4; ++kf) st[kf] = vz;
        __builtin_amdgcn_s_setprio(1);
#pragma unroll
        for (int kk = 0; kk < 2; ++kk)
#pragma unroll
          for (int kf = 0; kf < 4; ++kf)
            st[kf] = __builtin_amdgcn_mfma_f32_16x16x32_bf16(
                kfr[kf][kk], qf[half][kk], st[kf], 0, 0, 0);
        __builtin_amdgcn_s_setprio(0);

        if (kt == ktm) {   // diagonal tile: causal mask
          int qg = q0h[half] + lr;
#pragma unroll
          for (int kf = 0; kf < 4; ++kf)
#pragma unroll
            for (int r = 0; r < 4; ++r) {
              int kg = kt * 64 + kf * 16 + lg * 4 + r;
              if (kg > qg) st[kf][r] = -1e30f;
            }
        }

        float tmx = -1e30f;
#pragma unroll
        for (int kf = 0; kf < 4; ++kf)
#pragma unroll
          for (int r = 0; r < 4; ++r) tmx = fmaxf(tmx, st[kf][r]);
        tmx = fmaxf(tmx, __shfl_xor(tmx, 16));
        tmx = fmaxf(tmx, __shfl_xor(tmx, 32));

        float mo = m_[half];
        if (!__all(tmx <= mo + 8.f)) {   // defer-max (log2 domain, P <= 2^8)
          float mn = fmaxf(mo, tmx);
          float rsc = exp2f(mo - mn);
          l_[half] *= rsc;
#pragma unroll
          for (int df = 0; df < 4; ++df) acc[half][df] *= rsc;
          m_[half] = mn;
        }
        float mb = m_[half];
        float ts = 0.f;
        bf16x4 pb[4];
#pragma unroll
        for (int kf = 0; kf < 4; ++kf) {
#pragma unroll
          for (int r = 0; r < 4; ++r) {
            float e = exp2f(st[kf][r] - mb);
            st[kf][r] = e;
            ts += e;
          }
          u32 w0, w1;
          asm("v_cvt_pk_bf16_f32 %0, %1, %2" : "=v"(w0) : "v"(st[kf][0]), "v"(st[kf][1]));
          asm("v_cvt_pk_bf16_f32 %0, %1, %2" : "=v"(w1) : "v"(st[kf][2]), "v"(st[kf][3]));
          union { u32 u[2]; bf16x4 v; } pk;
          pk.u[0] = w0; pk.u[1] = w1;
          pb[kf] = pk.v;
        }
        ts += __shfl_xor(ts, 16);
        ts += __shfl_xor(ts, 32);
        l_[half] += ts;

        __builtin_amdgcn_s_setprio(1);
#pragma unroll
        for (int df = 0; df < 4; ++df) {
          int row = df * 16 + lr;
#pragma unroll
          for (int kf = 0; kf < 4; ++kf) {
            int slot = (kf * 2 + (lg >> 1)) ^ (row & 7);
            bf16x4 vfr = *(const bf16x4*)&Vl[cur][row * 64 + slot * 8 + (lg & 1) * 4];
            acc[half][df] = __builtin_amdgcn_mfma_f32_16x16x16bf16_1k(
                vfr, pb[kf], acc[half][df], 0, 0, 0);
          }
        }
        __builtin_amdgcn_s_setprio(0);
      }
    }
    __builtin_amdgcn_sched_barrier(0);
    __builtin_amdgcn_s_barrier();
  }

  // epilogue: O[q][h*64+d] = acc / l
#pragma unroll
  for (int half = 0; half < 2; ++half) {
    float inv = 1.0f / l_[half];
    int grow = bS + q0h[half] + lr;
#pragma unroll
    for (int df = 0; df < 4; ++df) {
      u64 pk = (u64)f2bf(acc[half][df][0] * inv) |
               ((u64)f2bf(acc[half][df][1] * inv) << 16) |
               ((u64)f2bf(acc[half][df][2] * inv) << 32) |
               ((u64)f2bf(acc[half][df][3] * inv) << 48);
      *(u64*)&O[(size_t)grow * HID_ + h * HD_ + df * 16 + lg * 4] = pk;
    }
  }
}

// ---------------- launch ----------------
extern "C" void kernel_launch(void* const* d_in, const int* in_sizes, int n_in,
                              void* d_out, int out_size, void* d_ws, size_t ws_size,
                              hipStream_t stream) {
  const float* hs = (const float*)d_in[0];
  const float* wq = (const float*)d_in[2];
  const float* wk = (const float*)d_in[3];
  const float* wv = (const float*)d_in[4];
  const float* wo = (const float*)d_in[5];
  float* out = (float*)d_out;

  char* ws = (char*)d_ws;
  const size_t P = (size_t)MR_ * HID_ * 2;   // 8 MiB plane
  u16* Xb  = (u16*)(ws);                     // plane 0; reused as attn_o
  u16* Wqb = (u16*)(ws + P);
  u16* Wkb = (u16*)(ws + P + (size_t)HID_ * HID_ * 2);
  u16* Wvb = (u16*)(ws + P + (size_t)HID_ * HID_ * 4);
  u16* Wob = (u16*)(ws + P + (size_t)HID_ * HID_ * 6);
  u16* q_r = (u16*)(ws + 2 * P);
  u16* k_r = (u16*)(ws + 3 * P);
  u16* vt  = (u16*)(ws + 4 * P);
  float2* tab = (float2*)(ws + 5 * P);
  u16* attn_o = Xb;

  // converts + rope table
  k_cvt_all<<<8192, 256, 0, stream>>>(hs, wq, wk, wv, wo, (ushort4*)ws);
  k_rope_table<<<256, 256, 0, stream>>>(tab);

  // QKV projections with fused RoPE (q,k) + V-transpose epilogues
  k_gemm_bt<0><<<dim3(24, 32), 256, 0, stream>>>(
      Xb, Wqb, Wkb, Wvb, q_r, k_r, vt, nullptr, tab, HID_);

  // attention
  k_attn<<<512, 256, 0, stream>>>(q_r, k_r, vt, attn_o);

  // output projection -> f32
  k_gemm_bt<1><<<dim3(8, 32), 256, 0, stream>>>(
      attn_o, Wob, Wob, Wob, nullptr, nullptr, nullptr, out, nullptr, HID_);
}

// Round 4
// 128.933 us; speedup vs baseline: 1.5461x; 1.1459x over previous
//
#include <hip/hip_runtime.h>
#include <hip/hip_bf16.h>
#include <math.h>

typedef unsigned short u16;
typedef unsigned int   u32;
typedef unsigned long long u64;
typedef __attribute__((ext_vector_type(8))) short bf16x8;
typedef __attribute__((ext_vector_type(4))) short bf16x4;
typedef __attribute__((ext_vector_type(4))) float f32x4;

#define B_   2
#define S_   2048
#define HID_ 1024
#define NH_  16
#define HD_  64
#define MR_  (B_*S_)   // 4096 rows

// 0.125 * log2(e) : folds the 1/sqrt(64) score scale and exp->exp2 into Q.
#define QSCALE 0.1803368801111137f

__device__ __forceinline__ u16 f2bf(float f) {
  union { float f; u32 u; } x; x.f = f;
  u32 r = x.u + 0x7fffu + ((x.u >> 16) & 1u);
  return (u16)(r >> 16);
}
__device__ __forceinline__ void gload16(const void* g, void* l) {
  __builtin_amdgcn_global_load_lds(
      (const __attribute__((address_space(1))) u32*)g,
      (__attribute__((address_space(3))) u32*)l, 16, 0, 0);
}

// ---------------- fused f32 -> bf16 convert (hs + 4 weights) ----------------
__global__ void k_cvt_all(const float* __restrict__ hs, const float* __restrict__ wq,
                          const float* __restrict__ wk, const float* __restrict__ wv,
                          const float* __restrict__ wo, ushort4* __restrict__ dst) {
  int i = blockIdx.x * blockDim.x + threadIdx.x;   // < 2097152
  const float4* src;
  int idx;
  if (i < 1048576) {
    src = (const float4*)hs; idx = i;
  } else {
    int j = i - 1048576;
    int w = j >> 18; idx = j & 262143;
    src = (const float4*)(w == 0 ? wq : w == 1 ? wk : w == 2 ? wv : wo);
  }
  float4 v = src[idx];
  ushort4 o;
  o.x = f2bf(v.x); o.y = f2bf(v.y); o.z = f2bf(v.z); o.w = f2bf(v.w);
  dst[i] = o;
}

// ---------------- rope table (exact reference gather semantics) ----------------
__global__ void k_rope_table(float2* __restrict__ tab) {
  int t = blockIdx.x * blockDim.x + threadIdx.x;   // < 65536
  int p = t >> 5, j = t & 31;
  double fp = (double)p;
  double c, s;
  if (j < 16) {
    s = sin(fp * pow(10000.0, -(2.0 * j) / 32.0));
    c = sin(fp * pow(10000.0, -(2.0 * j + 1.0) / 32.0));
  } else {
    s = cos(fp * pow(10000.0, -(2.0 * j - 32.0) / 32.0));
    c = cos(fp * pow(10000.0, -(2.0 * j - 31.0) / 32.0));
  }
  tab[p * 32 + j] = make_float2((float)c, (float)s);
}

// ---------------- GEMM: BMx128 tile, BK=64, fused epilogues ----------------
// MODE 0: QKV (BM=128) — wi 0/1 apply RoPE in-epilogue; wi 2 writes V
//         transposed to vt[bh][d][s].
// MODE 1: f32 output (O-projection), BM=64 for occupancy.
template <int MODE, int BM>
__global__ __launch_bounds__(256) void k_gemm_bt(
    const u16* __restrict__ A,
    const u16* __restrict__ W0, const u16* __restrict__ W1, const u16* __restrict__ W2,
    u16* __restrict__ O0, u16* __restrict__ O1, u16* __restrict__ O2,
    float* __restrict__ OF, const float2* __restrict__ tab, int K) {
  constexpr int MI = BM / 32;        // m-fragments per wave
  constexpr int WR = BM / 2;         // rows per wave-row-group
  __shared__ __align__(16) u16 Al[BM * 64];
  __shared__ __align__(16) u16 Bl[128 * 64];

  int tid = threadIdx.x;
  int lane = tid & 63, wave = tid >> 6;
  int m0 = blockIdx.y * BM;
  int nt0 = blockIdx.x * 128;
  int wi = nt0 >> 10;
  const u16* W = (wi == 0) ? W0 : (wi == 1 ? W1 : W2);
  int n0 = nt0 & 1023;
  int wm = wave >> 1, wn = wave & 1;
  int lg = lane >> 4, lr = lane & 15;

  f32x4 acc[MI][4];
  const f32x4 vz = {0.f, 0.f, 0.f, 0.f};
#pragma unroll
  for (int i = 0; i < MI; ++i)
#pragma unroll
    for (int j = 0; j < 4; ++j) acc[i][j] = vz;

  int chunk = wave * 64 + lane;

  for (int k0 = 0; k0 < K; k0 += 64) {
#pragma unroll
    for (int it = 0; it < BM / 32; ++it) {
      int c = it * 256 + chunk;
      int row = c >> 3;
      int cw = (c & 7) ^ (row & 7);
      gload16(&A[(size_t)(m0 + row) * K + k0 + cw * 8], &Al[(it * 256 + wave * 64) * 8]);
    }
#pragma unroll
    for (int it = 0; it < 4; ++it) {
      int c = it * 256 + chunk;
      int row = c >> 3;
      int cw = (c & 7) ^ (row & 7);
      gload16(&W[(size_t)(n0 + row) * K + k0 + cw * 8], &Bl[(it * 256 + wave * 64) * 8]);
    }
    __syncthreads();
#pragma unroll
    for (int kk = 0; kk < 2; ++kk) {
      bf16x8 af[MI], bfr[4];
#pragma unroll
      for (int mi = 0; mi < MI; ++mi) {
        int row = wm * WR + mi * 16 + lr;
        int ci = (kk * 4 + lg) ^ (row & 7);
        af[mi] = *(const bf16x8*)&Al[row * 64 + ci * 8];
      }
#pragma unroll
      for (int ni = 0; ni < 4; ++ni) {
        int row = wn * 64 + ni * 16 + lr;
        int ci = (kk * 4 + lg) ^ (row & 7);
        bfr[ni] = *(const bf16x8*)&Bl[row * 64 + ci * 8];
      }
#pragma unroll
      for (int mi = 0; mi < MI; ++mi)
#pragma unroll
        for (int ni = 0; ni < 4; ++ni)
          acc[mi][ni] = __builtin_amdgcn_mfma_f32_16x16x32_bf16(af[mi], bfr[ni], acc[mi][ni], 0, 0, 0);
    }
    __syncthreads();
  }

  if (MODE == 1) {
#pragma unroll
    for (int mi = 0; mi < MI; ++mi)
#pragma unroll
      for (int ni = 0; ni < 4; ++ni)
#pragma unroll
        for (int r = 0; r < 4; ++r) {
          int grow = m0 + wm * WR + mi * 16 + lg * 4 + r;
          int gcol = n0 + wn * 64 + ni * 16 + lr;
          OF[(size_t)grow * 1024 + gcol] = acc[mi][ni][r];
        }
    return;
  }

  // MODE 0 epilogues
  if (wi == 2) {
    // V: write transposed vt[((b*16+h)*64 + d)*2048 + s], 4 rows packed per u64
#pragma unroll
    for (int mi = 0; mi < MI; ++mi) {
      int grow0 = m0 + wm * WR + mi * 16 + lg * 4;
      int bb = grow0 >> 11;
      int s = grow0 & 2047;
#pragma unroll
      for (int ni = 0; ni < 4; ++ni) {
        int gcol = n0 + wn * 64 + ni * 16 + lr;
        int h = gcol >> 6, dd = gcol & 63;
        u64 pk = (u64)f2bf(acc[mi][ni][0]) |
                 ((u64)f2bf(acc[mi][ni][1]) << 16) |
                 ((u64)f2bf(acc[mi][ni][2]) << 32) |
                 ((u64)f2bf(acc[mi][ni][3]) << 48);
        *(u64*)&O2[((size_t)(bb * NH_ + h) * HD_ + dd) * S_ + s] = pk;
      }
    }
  } else {
    // Q / K: RoPE in-epilogue. Pair (2j, 2j+1) lives in lanes (lr even, lr odd).
    u16* OB = wi ? O1 : O0;
    float sc = wi ? 1.0f : QSCALE;
#pragma unroll
    for (int mi = 0; mi < MI; ++mi) {
#pragma unroll
      for (int ni = 0; ni < 4; ++ni) {
        int gcol = n0 + wn * 64 + ni * 16 + lr;
        int h = gcol >> 6;
        int j = (gcol & 63) >> 1;
        bool even = !(gcol & 1);
        int ocol = h * 64 + (even ? j : 32 + j);
#pragma unroll
        for (int r = 0; r < 4; ++r) {
          float val = acc[mi][ni][r];
          float pv = __shfl_xor(val, 1);
          int grow = m0 + wm * WR + mi * 16 + lg * 4 + r;
          int s = grow & 2047;
          float2 cs = tab[s * 32 + j];
          float xe = even ? val : pv;
          float xo = even ? pv : val;
          float res = even ? (xe * cs.x - xo * cs.y) : (xe * cs.y + xo * cs.x);
          OB[(size_t)grow * 1024 + ocol] = f2bf(res * sc);
        }
      }
    }
  }
}

// ---------------- flash attention v4 ----------------
// One 64-row q-tile per block (4 waves x 16 rows). Grid 1024, LPT order:
// big tiles (qt=31) first; bh in low bits so bh%8 pins to XCD. 32KB LDS +
// launch_bounds(256,4) -> 4 blocks/CU resident (16 waves/CU).
__global__ __launch_bounds__(256, 4) void k_attn(
    const u16* __restrict__ Q, const u16* __restrict__ Kr, const u16* __restrict__ VT,
    u16* __restrict__ O) {
  __shared__ __align__(16) u16 Kl[2][64 * 64];
  __shared__ __align__(16) u16 Vl[2][64 * 64];

  int tid = threadIdx.x, lane = tid & 63, wave = tid >> 6;
  int id = blockIdx.x;                 // 0..1023
  int qt = 31 - (id >> 5);             // descending work (LPT)
  int bh = id & 31;
  int b = bh >> 4, h = bh & 15;
  int lg = lane >> 4, lr = lane & 15;
  int bS = b * S_;
  int nkt = qt + 1;
  int q0 = qt * 64 + wave * 16;

  const u16* vtb = &VT[(size_t)bh * HD_ * S_];
  int l8 = lane >> 3, l7 = lane & 7;
  int sl = l7 ^ l8;   // pre-swizzled global slot

  auto STAGE = [&](int kt_, int bs_) {
#pragma unroll
    for (int it = 0; it < 2; ++it) {
      int rb = wave * 16 + it * 8;     // wave-uniform LDS row base
      int r = rb + l8;
      gload16(&Kr[(size_t)(bS + kt_ * 64 + r) * HID_ + h * HD_ + sl * 8],
              &Kl[bs_][rb * 64]);
      gload16(&vtb[(size_t)r * S_ + kt_ * 64 + sl * 8],
              &Vl[bs_][rb * 64]);
    }
  };

  STAGE(0, 0);

  bf16x8 qf[2];
#pragma unroll
  for (int kk = 0; kk < 2; ++kk)
    qf[kk] = *(const bf16x8*)
        &Q[(size_t)(bS + q0 + lr) * HID_ + h * HD_ + kk * 32 + lg * 8];

  f32x4 acc[4];
  const f32x4 vz = {0.f, 0.f, 0.f, 0.f};
#pragma unroll
  for (int df = 0; df < 4; ++df) acc[df] = vz;
  float m_ = -1e30f;
  float l_ = 0.f;

  for (int kt = 0; kt < nkt; ++kt) {
    int cur = kt & 1;
    if (kt + 1 < nkt) {
      STAGE(kt + 1, cur ^ 1);
      asm volatile("s_waitcnt vmcnt(4)" ::: "memory");
    } else {
      asm volatile("s_waitcnt vmcnt(0)" ::: "memory");
    }
    __builtin_amdgcn_s_barrier();
    __builtin_amdgcn_sched_barrier(0);

    // K fragments
    bf16x8 kfr[4][2];
#pragma unroll
    for (int kf = 0; kf < 4; ++kf) {
      int row = kf * 16 + lr;
#pragma unroll
      for (int kk = 0; kk < 2; ++kk) {
        int ci = (kk * 4 + lg) ^ (row & 7);
        kfr[kf][kk] = *(const bf16x8*)&Kl[cur][row * 64 + ci * 8];
      }
    }

    // QK^T (swapped): st rows = keys, cols = q
    f32x4 st[4];
#pragma unroll
    for (int kf = 0; kf < 4; ++kf) st[kf] = vz;
    __builtin_amdgcn_s_setprio(1);
#pragma unroll
    for (int kk = 0; kk < 2; ++kk)
#pragma unroll
      for (int kf = 0; kf < 4; ++kf)
        st[kf] = __builtin_amdgcn_mfma_f32_16x16x32_bf16(
            kfr[kf][kk], qf[kk], st[kf], 0, 0, 0);
    __builtin_amdgcn_s_setprio(0);

    if (kt == qt) {   // diagonal tile: causal mask
      int qg = q0 + lr;
#pragma unroll
      for (int kf = 0; kf < 4; ++kf)
#pragma unroll
        for (int r = 0; r < 4; ++r) {
          int kg = kt * 64 + kf * 16 + lg * 4 + r;
          if (kg > qg) st[kf][r] = -1e30f;
        }
    }

    float tmx = -1e30f;
#pragma unroll
    for (int kf = 0; kf < 4; ++kf)
#pragma unroll
      for (int r = 0; r < 4; ++r) tmx = fmaxf(tmx, st[kf][r]);
    tmx = fmaxf(tmx, __shfl_xor(tmx, 16));
    tmx = fmaxf(tmx, __shfl_xor(tmx, 32));

    if (!__all(tmx <= m_ + 8.f)) {   // defer-max (log2 domain, P <= 2^8)
      float mn = fmaxf(m_, tmx);
      float rsc = __builtin_amdgcn_exp2f(m_ - mn);
      l_ *= rsc;
#pragma unroll
      for (int df = 0; df < 4; ++df) acc[df] *= rsc;
      m_ = mn;
    }
    float mb = m_;
    float ts = 0.f;
    bf16x4 pb[4];
#pragma unroll
    for (int kf = 0; kf < 4; ++kf) {
#pragma unroll
      for (int r = 0; r < 4; ++r) {
        float e = __builtin_amdgcn_exp2f(st[kf][r] - mb);
        st[kf][r] = e;
        ts += e;
      }
      u32 w0, w1;
      asm("v_cvt_pk_bf16_f32 %0, %1, %2" : "=v"(w0) : "v"(st[kf][0]), "v"(st[kf][1]));
      asm("v_cvt_pk_bf16_f32 %0, %1, %2" : "=v"(w1) : "v"(st[kf][2]), "v"(st[kf][3]));
      union { u32 u[2]; bf16x4 v; } pk;
      pk.u[0] = w0; pk.u[1] = w1;
      pb[kf] = pk.v;
    }
    ts += __shfl_xor(ts, 16);
    ts += __shfl_xor(ts, 32);
    l_ += ts;

    // PV: O^T += V^T . P^T
    __builtin_amdgcn_s_setprio(1);
#pragma unroll
    for (int df = 0; df < 4; ++df) {
      int row = df * 16 + lr;
#pragma unroll
      for (int kf = 0; kf < 4; ++kf) {
        int slot = (kf * 2 + (lg >> 1)) ^ (row & 7);
        bf16x4 vfr = *(const bf16x4*)&Vl[cur][row * 64 + slot * 8 + (lg & 1) * 4];
        acc[df] = __builtin_amdgcn_mfma_f32_16x16x16bf16_1k(
            vfr, pb[kf], acc[df], 0, 0, 0);
      }
    }
    __builtin_amdgcn_s_setprio(0);

    __builtin_amdgcn_sched_barrier(0);
    __builtin_amdgcn_s_barrier();
  }

  // epilogue: O[q][h*64+d] = acc / l
  float inv = 1.0f / l_;
  int grow = bS + q0 + lr;
#pragma unroll
  for (int df = 0; df < 4; ++df) {
    u64 pk = (u64)f2bf(acc[df][0] * inv) |
             ((u64)f2bf(acc[df][1] * inv) << 16) |
             ((u64)f2bf(acc[df][2] * inv) << 32) |
             ((u64)f2bf(acc[df][3] * inv) << 48);
    *(u64*)&O[(size_t)grow * HID_ + h * HD_ + df * 16 + lg * 4] = pk;
  }
}

// ---------------- launch ----------------
extern "C" void kernel_launch(void* const* d_in, const int* in_sizes, int n_in,
                              void* d_out, int out_size, void* d_ws, size_t ws_size,
                              hipStream_t stream) {
  const float* hs = (const float*)d_in[0];
  const float* wq = (const float*)d_in[2];
  const float* wk = (const float*)d_in[3];
  const float* wv = (const float*)d_in[4];
  const float* wo = (const float*)d_in[5];
  float* out = (float*)d_out;

  char* ws = (char*)d_ws;
  const size_t P = (size_t)MR_ * HID_ * 2;   // 8 MiB plane
  u16* Xb  = (u16*)(ws);                     // plane 0; reused as attn_o
  u16* Wqb = (u16*)(ws + P);
  u16* Wkb = (u16*)(ws + P + (size_t)HID_ * HID_ * 2);
  u16* Wvb = (u16*)(ws + P + (size_t)HID_ * HID_ * 4);
  u16* Wob = (u16*)(ws + P + (size_t)HID_ * HID_ * 6);
  u16* q_r = (u16*)(ws + 2 * P);
  u16* k_r = (u16*)(ws + 3 * P);
  u16* vt  = (u16*)(ws + 4 * P);
  float2* tab = (float2*)(ws + 5 * P);
  u16* attn_o = Xb;

  // converts + rope table
  k_cvt_all<<<8192, 256, 0, stream>>>(hs, wq, wk, wv, wo, (ushort4*)ws);
  k_rope_table<<<256, 256, 0, stream>>>(tab);

  // QKV projections with fused RoPE (q,k) + V-transpose epilogues
  k_gemm_bt<0, 128><<<dim3(24, 32), 256, 0, stream>>>(
      Xb, Wqb, Wkb, Wvb, q_r, k_r, vt, nullptr, tab, HID_);

  // attention (LPT-ordered triangular blocks)
  k_attn<<<1024, 256, 0, stream>>>(q_r, k_r, vt, attn_o);

  // output projection -> f32 (BM=64 for 2 blocks/CU)
  k_gemm_bt<1, 64><<<dim3(8, 64), 256, 0, stream>>>(
      attn_o, Wob, Wob, Wob, nullptr, nullptr, nullptr, out, nullptr, HID_);
}